// Round 3
// baseline (140.005 us; speedup 1.0000x reference)
//
#include <hip/hip_runtime.h>
#include <math.h>

// HiddenTreeMarkovModel upward recursion.
// T_TREES=128, BR=2, DEPTH=11, C=8, L=2, M=256, G=4.
// Grid = 256 blocks: block = (tree t, g-pair), t = blockIdx.x>>1,
// g in {g0, g0+1} with g0 = 2*(blockIdx.x&1); per-thread gi = tid>>9 picks one g.
// Level offsets: offs[l] = 128*(2^l - 1); tree t owns [offs[l]+t*2^l, +2^l).
//
// Key layout decisions (round 3):
//  - A (both pv), Pi, SP live in VGPRs per thread (pv is per-lane data ->
//    LDS matvec was 64 ds_read_b32/node = LDS-pipe-bound; registers kill it).
//  - Bm stored transposed [gi][m][c] so the per-node emission gather is
//    2x ds_read_b128 instead of 8 conflicted ds_read_b32.
//  - log accumulated in log2 domain (__log2f), scaled by ln2 once at end.

#define NTHREADS 1024
#define NSTRIDE 17   // odd node stride in beta buffers: writes conflict-free

__global__ __launch_bounds__(NTHREADS) void htmm_kernel(
    const float* __restrict__ lA,   // (C,C,L,G)  c*64 + d*8 + p*4 + g
    const float* __restrict__ lB,   // (C,M,G)    c*1024 + m*4 + g
    const float* __restrict__ lPi,  // (C,L,G)    c*8 + p*4 + g
    const float* __restrict__ lSP,  // (L,G)      p*4 + g
    const int* __restrict__ pos,
    const int* __restrict__ xx,
    float* __restrict__ out)        // (128,4)
{
    __shared__ __align__(16) float sBm[2 * 256 * 8];  // [gi][m][c]
    __shared__ __align__(16) float sA[256];           // [((p*2+gi)*8+c)*8+d]
    __shared__ __align__(16) float sPi[32];           // [(p*2+gi)*8+c]
    __shared__ float sSP[4];                          // [p*2+gi]
    __shared__ float sInv[16];                        // [gi*8+c]
    __shared__ float buf0[512 * NSTRIDE];
    __shared__ float buf1[256 * NSTRIDE];
    __shared__ double sLL[2];

    const int tid = threadIdx.x;
    const int t  = blockIdx.x >> 1;
    const int g0 = (blockIdx.x & 1) << 1;

    if (tid < 2) sLL[tid] = 0.0;

    // ---------- softmax tables (our 2 g's only) ----------
    // Bm exp pass: 4096 elems, layout [gi][m][c]
#pragma unroll
    for (int k = 0; k < 4; ++k) {
        int w = tid + k * NTHREADS;
        int gg = w >> 11, m = (w >> 3) & 255, c = w & 7;
        sBm[w] = expf(lB[c * 1024 + m * 4 + g0 + gg]);
    }
    __syncthreads();

    if (tid < 256) {
        // row sums over m for each (gi,c): 16 rows x 16 threads
        int r = tid >> 4, seg = tid & 15;       // r = gi*8 + c
        int gg = r >> 3, c = r & 7;
        float s = 0.f;
#pragma unroll
        for (int i = 0; i < 16; ++i)
            s += sBm[(gg << 11) + ((seg * 16 + i) << 3) + c];
#pragma unroll
        for (int o = 8; o >= 1; o >>= 1) s += __shfl_xor(s, o, 64);
        if (seg == 0) sInv[r] = 1.0f / s;
    } else if (tid >= 256 && tid < 288) {
        // A softmax over c, per (d,p,gi)
        int w = tid - 256;
        int d = w >> 2, pp = (w >> 1) & 1, gg = w & 1;
        float e[8]; float s = 0.f;
#pragma unroll
        for (int c = 0; c < 8; ++c) { e[c] = expf(lA[c * 64 + d * 8 + pp * 4 + g0 + gg]); s += e[c]; }
        float inv = 1.f / s;
#pragma unroll
        for (int c = 0; c < 8; ++c) sA[(((pp << 1) | gg) * 8 + c) * 8 + d] = e[c] * inv;
    } else if (tid >= 288 && tid < 292) {
        int w = tid - 288; int pp = w >> 1, gg = w & 1;
        float e[8]; float s = 0.f;
#pragma unroll
        for (int c = 0; c < 8; ++c) { e[c] = expf(lPi[c * 8 + pp * 4 + g0 + gg]); s += e[c]; }
        float inv = 1.f / s;
#pragma unroll
        for (int c = 0; c < 8; ++c) sPi[((pp << 1) | gg) * 8 + c] = e[c] * inv;
    } else if (tid >= 292 && tid < 294) {
        int gg = tid - 292;
        float e0 = expf(lSP[g0 + gg]), e1 = expf(lSP[4 + g0 + gg]);
        float inv = 1.f / (e0 + e1);
        sSP[gg] = e0 * inv; sSP[2 + gg] = e1 * inv;
    }
    __syncthreads();

    // Bm normalize
#pragma unroll
    for (int k = 0; k < 4; ++k) {
        int w = tid + k * NTHREADS;
        sBm[w] *= sInv[((w >> 11) << 3) + (w & 7)];
    }
    __syncthreads();

    // ---------- hoist A / Pi / SP into registers ----------
    const int gi = tid >> 9;        // wave-uniform
    const int j  = tid & 511;       // level-9 node within tree

    float A0r[64], A1r[64];
    {
        const float4* a0 = (const float4*)(sA + (gi << 6));
        const float4* a1 = (const float4*)(sA + ((2 + gi) << 6));
#pragma unroll
        for (int q = 0; q < 16; ++q) {
            float4 v0 = a0[q];
            A0r[4 * q + 0] = v0.x; A0r[4 * q + 1] = v0.y; A0r[4 * q + 2] = v0.z; A0r[4 * q + 3] = v0.w;
            float4 v1 = a1[q];
            A1r[4 * q + 0] = v1.x; A1r[4 * q + 1] = v1.y; A1r[4 * q + 2] = v1.z; A1r[4 * q + 3] = v1.w;
        }
    }
    float Pi0r[8], Pi1r[8];
#pragma unroll
    for (int c = 0; c < 8; ++c) { Pi0r[c] = sPi[(gi << 3) + c]; Pi1r[c] = sPi[((2 + gi) << 3) + c]; }
    const float SP0 = sSP[gi], SP1 = sSP[2 + gi];

    float llacc = 0.f;   // log2 domain

    // register-only 8x8 matvec with per-lane pv select, acc[c] += scale * (A_pv . b)
    auto matvec_acc = [&](const float (&b)[8], int pv, float scale, float (&acc)[8]) {
        float s0[8], s1[8];
#pragma unroll
        for (int c = 0; c < 8; ++c) { s0[c] = 0.f; s1[c] = 0.f; }
#pragma unroll
        for (int c = 0; c < 8; ++c) {
#pragma unroll
            for (int d = 0; d < 8; ++d) {
                s0[c] += A0r[(c << 3) + d] * b[d];
                s1[c] += A1r[(c << 3) + d] * b[d];
            }
        }
#pragma unroll
        for (int c = 0; c < 8; ++c) acc[c] += scale * (pv ? s1[c] : s0[c]);
    };

    auto bm_gather = [&](int xv, float (&bm)[8]) {
        const float4 v0 = *(const float4*)(sBm + (gi << 11) + (xv << 3));
        const float4 v1 = *(const float4*)(sBm + (gi << 11) + (xv << 3) + 4);
        bm[0] = v0.x; bm[1] = v0.y; bm[2] = v0.z; bm[3] = v0.w;
        bm[4] = v1.x; bm[5] = v1.y; bm[6] = v1.z; bm[7] = v1.w;
    };

    // ---------- stage 1: fused levels 11,10,9 ----------
    {
        const int4 pv4 = *(const int4*)(pos + 262016 + t * 2048 + 4 * j);
        const int4 xv4 = *(const int4*)(xx  + 262016 + t * 2048 + 4 * j);
        const int2 pu2 = *(const int2*)(pos + 130944 + t * 1024 + 2 * j);
        const int2 xu2 = *(const int2*)(xx  + 130944 + t * 1024 + 2 * j);
        const int xq = xx[65408 + t * 512 + j];

        float tq[8] = {0,0,0,0,0,0,0,0};
#pragma unroll
        for (int u = 0; u < 2; ++u) {
            float tu[8] = {0,0,0,0,0,0,0,0};
#pragma unroll
            for (int v = 0; v < 2; ++v) {
                const int k = 2 * u + v;
                const int pv  = (k == 0) ? pv4.x : (k == 1) ? pv4.y : (k == 2) ? pv4.z : pv4.w;
                const int xvv = (k == 0) ? xv4.x : (k == 1) ? xv4.y : (k == 2) ? xv4.z : xv4.w;
                float bm[8]; bm_gather(xvv, bm);
                float b[8]; float nu = 0.f;
#pragma unroll
                for (int c = 0; c < 8; ++c) {
                    b[c] = (pv ? Pi1r[c] : Pi0r[c]) * bm[c];
                    nu += b[c];
                }
                llacc += __log2f(nu);
                const float scale = (pv ? SP1 : SP0) / nu;  // fold normalization
                matvec_acc(b, pv, scale, tu);
            }
            const int pu = u ? pu2.y : pu2.x;
            const int xu = u ? xu2.y : xu2.x;
            float bm[8]; bm_gather(xu, bm);
            float bu[8]; float nuu = 0.f;
#pragma unroll
            for (int c = 0; c < 8; ++c) { bu[c] = tu[c] * bm[c]; nuu += bu[c]; }
            llacc += __log2f(nuu);
            const float scale = (pu ? SP1 : SP0) / nuu;
            matvec_acc(bu, pu, scale, tq);
        }
        float bm[8]; bm_gather(xq, bm);
        float bq[8]; float nuq = 0.f;
#pragma unroll
        for (int c = 0; c < 8; ++c) { bq[c] = tq[c] * bm[c]; nuq += bq[c]; }
        llacc += __log2f(nuq);
        const float inv = 1.f / nuq;
#pragma unroll
        for (int c = 0; c < 8; ++c) buf0[j * NSTRIDE + (gi << 3) + c] = bq[c] * inv;
    }
    __syncthreads();

    // ---------- stage 2: levels 9 -> 0 ----------
    // active threads: (tid&511) < nP, each handles parent p for its own gi
    float* bin = buf0;
    float* bout = buf1;
    for (int l = 9; l >= 1; --l) {
        const int nP = 1 << (l - 1);
        const int chBase = 128 * ((1 << l) - 1) + t * (1 << l);
        const int paBase = 128 * (nP - 1) + t * nP;
        if (j < nP) {
            const int p = j;
            const int2 pch = *(const int2*)(pos + chBase + 2 * p);
            const int xpa = xx[paBase + p];
            float tp[8] = {0,0,0,0,0,0,0,0};
#pragma unroll
            for (int u = 0; u < 2; ++u) {
                const int pw = u ? pch.y : pch.x;
                const float* bip = &bin[(2 * p + u) * NSTRIDE + (gi << 3)];
                float b[8];
#pragma unroll
                for (int d = 0; d < 8; ++d) b[d] = bip[d];
                matvec_acc(b, pw, pw ? SP1 : SP0, tp);
            }
            float bm[8]; bm_gather(xpa, bm);
            float bpv[8]; float nu = 0.f;
#pragma unroll
            for (int c = 0; c < 8; ++c) { bpv[c] = tp[c] * bm[c]; nu += bpv[c]; }
            llacc += __log2f(nu);
            const float inv = 1.f / nu;
#pragma unroll
            for (int c = 0; c < 8; ++c) bout[p * NSTRIDE + (gi << 3) + c] = bpv[c] * inv;
        }
        __syncthreads();
        float* tmpp = bin; bin = bout; bout = tmpp;
    }

    // ---------- final log-likelihood reduction ----------
    float llf = llacc * 0.69314718055994530942f;   // log2 -> ln
#pragma unroll
    for (int o = 32; o >= 1; o >>= 1) llf += __shfl_xor(llf, o, 64);
    if ((tid & 63) == 0) atomicAdd(&sLL[gi], (double)llf);   // gi wave-uniform
    __syncthreads();
    if (tid < 2) out[(t << 2) + g0 + tid] = (float)sLL[tid];
}

extern "C" void kernel_launch(void* const* d_in, const int* in_sizes, int n_in,
                              void* d_out, int out_size, void* d_ws, size_t ws_size,
                              hipStream_t stream) {
    const float* lA  = (const float*)d_in[0];
    const float* lB  = (const float*)d_in[1];
    const float* lPi = (const float*)d_in[2];
    const float* lSP = (const float*)d_in[3];
    const int*   pos = (const int*)d_in[4];
    const int*   xv  = (const int*)d_in[5];
    float* out = (float*)d_out;
    htmm_kernel<<<256, NTHREADS, 0, stream>>>(lA, lB, lPi, lSP, pos, xv, out);
}

// Round 5
// 95.106 us; speedup vs baseline: 1.4721x; 1.4721x over previous
//
#include <hip/hip_runtime.h>
#include <math.h>

// HiddenTreeMarkovModel upward recursion.
// T_TREES=128, BR=2, DEPTH=11, C=8, L=2, M=256, G=4.
// Grid = 512 blocks: block = (tree t, generative head g), t = blockIdx.x>>2,
// g = blockIdx.x&3. 512 threads = 8 waves = 2 waves/SIMD at 1 block/CU.
//
// Round-5 geometry fix: round 3 spilled because a 1024-thread block can never
// exceed a 128-VGPR cap (16 waves -> >=4 waves/SIMD; pool=512/SIMD). The
// ~210-reg working set (A0r+A1r=128) needs a 256 cap -> 512-thread blocks
// with __launch_bounds__(512, 2). Math pipeline identical to the PASSED
// round-3 kernel (register 8x8 matvec + pv cndmask, __log2f accumulation,
// [m][c]-transposed Bm for b128 emission gathers).
// Level offsets: offs[l] = 128*(2^l - 1); tree t owns [offs[l]+t*2^l, +2^l).

#define NTHREADS 512
#define NSTRIDE 9   // odd per-node float stride in beta buffers (8 c + 1 pad)

__global__ __launch_bounds__(NTHREADS, 2) void htmm_kernel(
    const float* __restrict__ lA,   // (C,C,L,G)  c*64 + d*8 + p*4 + g
    const float* __restrict__ lB,   // (C,M,G)    c*1024 + m*4 + g
    const float* __restrict__ lPi,  // (C,L,G)    c*8 + p*4 + g
    const float* __restrict__ lSP,  // (L,G)      p*4 + g
    const int* __restrict__ pos,
    const int* __restrict__ xx,
    float* __restrict__ out)        // (128,4)
{
    __shared__ __align__(16) float sBm[256 * 8];  // [m][c]
    __shared__ __align__(16) float sA[128];       // [pv*64 + c*8 + d]
    __shared__ __align__(16) float sPi[16];       // [pv*8 + c]
    __shared__ float sSP[2];                      // [pv]
    __shared__ float sInv[8];                     // [c]
    __shared__ float buf0[512 * NSTRIDE];         // levels 9,7,5,3,1
    __shared__ float buf1[256 * NSTRIDE];         // levels 8,6,4,2,0
    __shared__ double sLL;

    const int tid = threadIdx.x;
    const int t = blockIdx.x >> 2;
    const int g = blockIdx.x & 3;

    if (tid == 0) sLL = 0.0;

    // ---------- softmax tables (our g only) ----------
    // Bm exp pass: 2048 elems, layout [m][c]
#pragma unroll
    for (int k = 0; k < 4; ++k) {
        int w = tid + k * NTHREADS;
        int m = w >> 3, c = w & 7;
        sBm[w] = expf(lB[c * 1024 + m * 4 + g]);
    }
    __syncthreads();

    if (tid < 128) {
        // row sums over m per c: 8 rows x 16 threads, staggered (<=4-way)
        int c = tid >> 4, seg = tid & 15;
        float s = 0.f;
#pragma unroll
        for (int i = 0; i < 16; ++i)
            s += sBm[((seg * 16 + ((i + seg) & 15)) << 3) + c];
#pragma unroll
        for (int o = 8; o >= 1; o >>= 1) s += __shfl_xor(s, o, 64);
        if (seg == 0) sInv[c] = 1.0f / s;
    } else if (tid >= 128 && tid < 144) {
        // A softmax over c, per (d,pv)
        int w = tid - 128;
        int d = w >> 1, pp = w & 1;
        float e[8]; float s = 0.f;
#pragma unroll
        for (int c = 0; c < 8; ++c) { e[c] = expf(lA[c * 64 + d * 8 + pp * 4 + g]); s += e[c]; }
        float inv = 1.f / s;
#pragma unroll
        for (int c = 0; c < 8; ++c) sA[pp * 64 + c * 8 + d] = e[c] * inv;
    } else if (tid >= 144 && tid < 146) {
        int pp = tid - 144;
        float e[8]; float s = 0.f;
#pragma unroll
        for (int c = 0; c < 8; ++c) { e[c] = expf(lPi[c * 8 + pp * 4 + g]); s += e[c]; }
        float inv = 1.f / s;
#pragma unroll
        for (int c = 0; c < 8; ++c) sPi[pp * 8 + c] = e[c] * inv;
    } else if (tid == 146) {
        float e0 = expf(lSP[g]), e1 = expf(lSP[4 + g]);
        float inv = 1.f / (e0 + e1);
        sSP[0] = e0 * inv; sSP[1] = e1 * inv;
    }
    __syncthreads();

    // Bm normalize
#pragma unroll
    for (int k = 0; k < 4; ++k) {
        int w = tid + k * NTHREADS;
        sBm[w] *= sInv[w & 7];
    }
    __syncthreads();

    // ---------- hoist A / Pi / SP into registers ----------
    const int j = tid;   // level-9 node within tree

    float A0r[64], A1r[64];
    {
        const float4* a0 = (const float4*)(sA);
        const float4* a1 = (const float4*)(sA + 64);
#pragma unroll
        for (int q = 0; q < 16; ++q) {
            float4 v0 = a0[q];
            A0r[4 * q + 0] = v0.x; A0r[4 * q + 1] = v0.y; A0r[4 * q + 2] = v0.z; A0r[4 * q + 3] = v0.w;
            float4 v1 = a1[q];
            A1r[4 * q + 0] = v1.x; A1r[4 * q + 1] = v1.y; A1r[4 * q + 2] = v1.z; A1r[4 * q + 3] = v1.w;
        }
    }
    float Pi0r[8], Pi1r[8];
#pragma unroll
    for (int c = 0; c < 8; ++c) { Pi0r[c] = sPi[c]; Pi1r[c] = sPi[8 + c]; }
    const float SP0 = sSP[0], SP1 = sSP[1];

    float llacc = 0.f;   // log2 domain

    // register-only 8x8 matvec with per-lane pv select, acc[c] += scale * (A_pv . b)
    auto matvec_acc = [&](const float (&b)[8], int pv, float scale, float (&acc)[8]) {
        float s0[8], s1[8];
#pragma unroll
        for (int c = 0; c < 8; ++c) { s0[c] = 0.f; s1[c] = 0.f; }
#pragma unroll
        for (int c = 0; c < 8; ++c) {
#pragma unroll
            for (int d = 0; d < 8; ++d) {
                s0[c] += A0r[(c << 3) + d] * b[d];
                s1[c] += A1r[(c << 3) + d] * b[d];
            }
        }
#pragma unroll
        for (int c = 0; c < 8; ++c) acc[c] += scale * (pv ? s1[c] : s0[c]);
    };

    auto bm_gather = [&](int xv, float (&bm)[8]) {
        const float4 v0 = *(const float4*)(sBm + (xv << 3));
        const float4 v1 = *(const float4*)(sBm + (xv << 3) + 4);
        bm[0] = v0.x; bm[1] = v0.y; bm[2] = v0.z; bm[3] = v0.w;
        bm[4] = v1.x; bm[5] = v1.y; bm[6] = v1.z; bm[7] = v1.w;
    };

    // ---------- stage 1: fused levels 11,10,9 ----------
    {
        const int4 pv4 = *(const int4*)(pos + 262016 + t * 2048 + 4 * j);
        const int4 xv4 = *(const int4*)(xx  + 262016 + t * 2048 + 4 * j);
        const int2 pu2 = *(const int2*)(pos + 130944 + t * 1024 + 2 * j);
        const int2 xu2 = *(const int2*)(xx  + 130944 + t * 1024 + 2 * j);
        const int xq = xx[65408 + t * 512 + j];

        float tq[8] = {0,0,0,0,0,0,0,0};
#pragma unroll
        for (int u = 0; u < 2; ++u) {
            float tu[8] = {0,0,0,0,0,0,0,0};
#pragma unroll
            for (int v = 0; v < 2; ++v) {
                const int k = 2 * u + v;
                const int pv  = (k == 0) ? pv4.x : (k == 1) ? pv4.y : (k == 2) ? pv4.z : pv4.w;
                const int xvv = (k == 0) ? xv4.x : (k == 1) ? xv4.y : (k == 2) ? xv4.z : xv4.w;
                float bm[8]; bm_gather(xvv, bm);
                float b[8]; float nu = 0.f;
#pragma unroll
                for (int c = 0; c < 8; ++c) {
                    b[c] = (pv ? Pi1r[c] : Pi0r[c]) * bm[c];
                    nu += b[c];
                }
                llacc += __log2f(nu);
                const float scale = (pv ? SP1 : SP0) / nu;  // fold normalization
                matvec_acc(b, pv, scale, tu);
            }
            const int pu = u ? pu2.y : pu2.x;
            const int xu = u ? xu2.y : xu2.x;
            float bm[8]; bm_gather(xu, bm);
            float bu[8]; float nuu = 0.f;
#pragma unroll
            for (int c = 0; c < 8; ++c) { bu[c] = tu[c] * bm[c]; nuu += bu[c]; }
            llacc += __log2f(nuu);
            const float scale = (pu ? SP1 : SP0) / nuu;
            matvec_acc(bu, pu, scale, tq);
        }
        float bm[8]; bm_gather(xq, bm);
        float bq[8]; float nuq = 0.f;
#pragma unroll
        for (int c = 0; c < 8; ++c) { bq[c] = tq[c] * bm[c]; nuq += bq[c]; }
        llacc += __log2f(nuq);
        const float inv = 1.f / nuq;
#pragma unroll
        for (int c = 0; c < 8; ++c) buf0[j * NSTRIDE + c] = bq[c] * inv;
    }
    __syncthreads();

    // ---------- stage 2: levels 9 -> 0 ----------
    float* bin = buf0;
    float* bout = buf1;
    for (int l = 9; l >= 1; --l) {
        const int nP = 1 << (l - 1);
        const int chBase = 128 * ((1 << l) - 1) + t * (1 << l);
        const int paBase = 128 * (nP - 1) + t * nP;
        if (j < nP) {
            const int p = j;
            const int2 pch = *(const int2*)(pos + chBase + 2 * p);
            const int xpa = xx[paBase + p];
            float tp[8] = {0,0,0,0,0,0,0,0};
#pragma unroll
            for (int u = 0; u < 2; ++u) {
                const int pw = u ? pch.y : pch.x;
                const float* bip = &bin[(2 * p + u) * NSTRIDE];
                float b[8];
#pragma unroll
                for (int d = 0; d < 8; ++d) b[d] = bip[d];
                matvec_acc(b, pw, pw ? SP1 : SP0, tp);
            }
            float bm[8]; bm_gather(xpa, bm);
            float bpv[8]; float nu = 0.f;
#pragma unroll
            for (int c = 0; c < 8; ++c) { bpv[c] = tp[c] * bm[c]; nu += bpv[c]; }
            llacc += __log2f(nu);
            const float inv = 1.f / nu;
#pragma unroll
            for (int c = 0; c < 8; ++c) bout[p * NSTRIDE + c] = bpv[c] * inv;
        }
        __syncthreads();
        float* tmpp = bin; bin = bout; bout = tmpp;
    }

    // ---------- final log-likelihood reduction ----------
    float llf = llacc * 0.69314718055994530942f;   // log2 -> ln
#pragma unroll
    for (int o = 32; o >= 1; o >>= 1) llf += __shfl_xor(llf, o, 64);
    if ((tid & 63) == 0) atomicAdd(&sLL, (double)llf);
    __syncthreads();
    if (tid == 0) out[(t << 2) | g] = (float)sLL;
}

extern "C" void kernel_launch(void* const* d_in, const int* in_sizes, int n_in,
                              void* d_out, int out_size, void* d_ws, size_t ws_size,
                              hipStream_t stream) {
    const float* lA  = (const float*)d_in[0];
    const float* lB  = (const float*)d_in[1];
    const float* lPi = (const float*)d_in[2];
    const float* lSP = (const float*)d_in[3];
    const int*   pos = (const int*)d_in[4];
    const int*   xv  = (const int*)d_in[5];
    float* out = (float*)d_out;
    htmm_kernel<<<512, NTHREADS, 0, stream>>>(lA, lB, lPi, lSP, pos, xv, out);
}